// Round 4
// baseline (456.409 us; speedup 1.0000x reference)
//
#include <hip/hip_runtime.h>
#include <math.h>

// Problem constants
#define B_    8
#define E_    512
#define L_    8192
#define K_    5
#define LC    8188      // L - K + 1
#define LOUT  4096      // L / DS
#define LPAD  8256      // xT padded t-length (129 * 64), rows >= L_ are zero

typedef float  f32x4   __attribute__((ext_vector_type(4)));
typedef float  f32x16  __attribute__((ext_vector_type(16)));
typedef short  s16x4   __attribute__((ext_vector_type(4)));
typedef short  s16x8   __attribute__((ext_vector_type(8)));

__device__ __forceinline__ unsigned short f2bf(float f) {
    union { float f; unsigned u; } v; v.f = f;
    unsigned r = v.u + 0x7FFFu + ((v.u >> 16) & 1u);
    return (unsigned short)(r >> 16);
}
__device__ __forceinline__ float bf2f(unsigned short h) {
    union { unsigned u; float f; } v; v.u = ((unsigned)h) << 16;
    return v.f;
}

// ---------------------------------------------------------------------------
// Kernel 0: pack conv weight [e][i][k] fp32 -> Wtb[k][e][i] bf16
// ---------------------------------------------------------------------------
__global__ __launch_bounds__(256) void wt_kernel(const float* __restrict__ w,
                                                 unsigned short* __restrict__ Wtb) {
    int idx = blockIdx.x * 256 + threadIdx.x;
    if (idx >= E_ * E_ * K_) return;
    int i    = idx & (E_ - 1);
    int rest = idx >> 9;            // k*E + e
    int e    = rest & (E_ - 1);
    int k    = rest >> 9;
    Wtb[idx] = f2bf(w[((size_t)e * E_ + i) * K_ + k]);
}

// ---------------------------------------------------------------------------
// Kernel 1: transpose x[b][i][t] fp32 -> xT[b][t][i] bf16, t padded to LPAD
// with zeros. float4 global loads, 8-byte stores.
// ---------------------------------------------------------------------------
__global__ __launch_bounds__(256) void xt_kernel(const float* __restrict__ x,
                                                 unsigned short* __restrict__ xT) {
    __shared__ float s[64][65];
    const int b  = blockIdx.z;
    const int i0 = blockIdx.y * 64;
    const int t0 = blockIdx.x * 64;
    #pragma unroll
    for (int j = 0; j < 4; ++j) {
        int idx = threadIdx.x + j * 256;      // 0..1023
        int r  = idx >> 4;                    // i-offset 0..63
        int c4 = (idx & 15) * 4;              // t-offset
        f32x4 v = (f32x4)0.f;
        if (t0 < L_)   // block-uniform: t0 multiple of 64, L_ multiple of 64
            v = *(const f32x4*)&x[((size_t)b * E_ + i0 + r) * L_ + t0 + c4];
        s[c4 + 0][r] = v[0]; s[c4 + 1][r] = v[1];
        s[c4 + 2][r] = v[2]; s[c4 + 3][r] = v[3];
    }
    __syncthreads();
    #pragma unroll
    for (int j = 0; j < 4; ++j) {
        int idx = threadIdx.x + j * 256;
        int tt = idx >> 4, ig = (idx & 15) * 4;
        s16x4 o;
        o[0] = (short)f2bf(s[tt][ig + 0]);
        o[1] = (short)f2bf(s[tt][ig + 1]);
        o[2] = (short)f2bf(s[tt][ig + 2]);
        o[3] = (short)f2bf(s[tt][ig + 3]);
        *(s16x4*)&xT[((size_t)b * LPAD + t0 + tt) * E_ + i0 + ig] = o;
    }
}

// ---------------------------------------------------------------------------
// Kernel 2: implicit-GEMM conv via 32x32x16 bf16 MFMA + fused z-score partials.
// Block: 64e x 512t, 4 waves, wave = 64e x 128t (2x4 subtiles of 32x32).
// z partials per e-block written with PLAIN stores (waves own disjoint t).
// ---------------------------------------------------------------------------
__global__ __launch_bounds__(256, 2) void conv_mfma(const unsigned short* __restrict__ xT,
                                                    const unsigned short* __restrict__ Wtb,
                                                    const float* __restrict__ bias,
                                                    const float* __restrict__ sw,
                                                    unsigned short* __restrict__ y,
                                                    float* __restrict__ zpart) {
    __shared__ unsigned short Xs[520][40];   // rows padded to 80 B (conflict-free)
    __shared__ unsigned short Ws[K_][64][40];
    __shared__ float swb[128];               // [0:64) = score_w, [64:128) = bias

    const int tid  = threadIdx.x;
    const int nt   = blockIdx.x;
    const int b    = nt >> 4;
    const int tb   = (nt & 15) * 512;
    const int e0   = blockIdx.y * 64;
    const int wave = tid >> 6;
    const int lane = tid & 63;
    const int l32  = lane & 31;
    const int hi   = lane >> 5;
    const int wt0  = wave * 128;

    if (tid < 64)       swb[tid] = sw[e0 + tid];
    else if (tid < 128) swb[tid] = bias[e0 + tid - 64];

    f32x16 acc[2][4];
    #pragma unroll
    for (int es = 0; es < 2; ++es)
        #pragma unroll
        for (int ts = 0; ts < 4; ++ts) acc[es][ts] = (f32x16)0.f;

    const unsigned short* xbase = xT + ((size_t)b * LPAD + tb) * E_;

    s16x8 xpf[9];
    s16x8 wpf[5];

    auto load_tile = [&](int i0) {
        #pragma unroll
        for (int j = 0; j < 8; ++j) {
            int idx = tid + j * 256;
            int r = idx >> 2, c = idx & 3;
            xpf[j] = *(const s16x8*)(xbase + (size_t)r * E_ + i0 + c * 8);
        }
        {
            int idx = tid + 2048;
            if (idx < 2080) {
                int r = idx >> 2, c = idx & 3;
                xpf[8] = *(const s16x8*)(xbase + (size_t)r * E_ + i0 + c * 8);
            }
        }
        #pragma unroll
        for (int j = 0; j < 5; ++j) {
            int idx = tid + j * 256;
            int rl = idx >> 2, c = idx & 3;
            int k = rl >> 6, ep = rl & 63;
            wpf[j] = *(const s16x8*)(Wtb + ((size_t)(k * E_ + e0 + ep) * E_ + i0 + c * 8));
        }
    };
    auto store_tile = [&]() {
        #pragma unroll
        for (int j = 0; j < 8; ++j) {
            int idx = tid + j * 256;
            int r = idx >> 2, c = idx & 3;
            *(s16x8*)&Xs[r][c * 8] = xpf[j];
        }
        {
            int idx = tid + 2048;
            if (idx < 2080) {
                int r = idx >> 2, c = idx & 3;
                *(s16x8*)&Xs[r][c * 8] = xpf[8];
            }
        }
        #pragma unroll
        for (int j = 0; j < 5; ++j) {
            int idx = tid + j * 256;
            int rl = idx >> 2, c = idx & 3;
            int k = rl >> 6, ep = rl & 63;
            *(s16x8*)&Ws[k][ep][c * 8] = wpf[j];
        }
    };

    load_tile(0);
    for (int i0 = 0; i0 < E_; i0 += 32) {
        __syncthreads();
        store_tile();
        __syncthreads();
        if (i0 + 32 < E_) load_tile(i0 + 32);

        #pragma unroll
        for (int k = 0; k < K_; ++k) {
            #pragma unroll
            for (int kk = 0; kk < 2; ++kk) {
                const int co = kk * 16 + hi * 8;
                s16x8 a0 = *(const s16x8*)&Ws[k][l32][co];
                s16x8 a1 = *(const s16x8*)&Ws[k][32 + l32][co];
                #pragma unroll
                for (int ts = 0; ts < 4; ++ts) {
                    s16x8 bv = *(const s16x8*)&Xs[wt0 + ts * 32 + l32 + k][co];
                    acc[0][ts] = __builtin_amdgcn_mfma_f32_32x32x16_bf16(a0, bv, acc[0][ts], 0, 0, 0);
                    acc[1][ts] = __builtin_amdgcn_mfma_f32_32x32x16_bf16(a1, bv, acc[1][ts], 0, 0, 0);
                }
            }
        }
    }

    // Epilogue: bias add, y store (bf16), z partial via shuffle + plain store.
    // C/D layout (32x32): col(t)=lane&31, row(e)=(reg&3)+8*(reg>>2)+4*hi
    float* zrow = zpart + (((size_t)blockIdx.y * B_ + b) << 13);
    #pragma unroll
    for (int ts = 0; ts < 4; ++ts) {
        const int t = tb + wt0 + ts * 32 + l32;     // < 8192 always
        const bool tv = (t < LC);
        float zp = 0.f;
        #pragma unroll
        for (int es = 0; es < 2; ++es) {
            #pragma unroll
            for (int reg = 0; reg < 16; ++reg) {
                int er = es * 32 + (reg & 3) + 8 * (reg >> 2) + 4 * hi;
                float v = acc[es][ts][reg] + swb[64 + er];
                if (tv) y[((size_t)b * E_ + e0 + er) * LC + t] = f2bf(v);
                zp += swb[er] * v;
            }
        }
        zp += __shfl_xor(zp, 32);
        if (hi == 0) zrow[t] = zp;
    }
}

// ---------------------------------------------------------------------------
// Kernel 3: one block per (b,e) row. Stage full y row (bf16) + summed z row
// in LDS, then blend widths 1..3 with softmax and 2x downsample.
// ---------------------------------------------------------------------------
#define SYS 8200
__global__ __launch_bounds__(256) void out_kernel(const unsigned short* __restrict__ y,
                                                  const float* __restrict__ zpart,
                                                  float* __restrict__ out) {
    __shared__ float zs[SYS];
    __shared__ unsigned short ys[SYS];
    const int be  = blockIdx.x;          // b*E + e
    const int b   = be >> 9;
    const int tid = threadIdx.x;

    // zero tail [LC, SYS)
    for (int i = LC + tid; i < SYS; i += 256) { zs[i] = 0.f; ys[i] = 0; }
    // stage y row: 2047 chunks of 4 ushorts (8 B) = exactly 8188
    const unsigned short* yrow = y + (size_t)be * LC;
    for (int c = tid; c < 2047; c += 256)
        *(s16x4*)&ys[c * 4] = *(const s16x4*)(yrow + c * 4);
    // stage z row: sum 8 e-block partials, f32x4 chunks (2047*4 = 8188)
    const float* zb = zpart + ((size_t)b << 13);
    for (int c = tid; c < 2047; c += 256) {
        f32x4 s = (f32x4)0.f;
        #pragma unroll
        for (int p = 0; p < 8; ++p)
            s += *(const f32x4*)(zb + ((size_t)(p * B_) << 13) + c * 4);
        *(f32x4*)&zs[c * 4] = s;
    }
    __syncthreads();

    float* orow = out + (size_t)be * LOUT;
    #pragma unroll
    for (int j = 0; j < 16; ++j) {
        const int d = j * 256 + tid;
        float o = 0.f;
        #pragma unroll
        for (int half = 0; half < 2; ++half) {
            int t = 2 * d + half;
            float C1 = bf2f(ys[t]);
            float S1 = zs[t];
            int i2 = t & ~1;
            float C2 = 0.5f * (bf2f(ys[i2]) + bf2f(ys[i2 + 1]));
            float S2 = 0.5f * (zs[i2] + zs[i2 + 1]);
            int i3 = (t / 3) * 3;
            float C3 = (bf2f(ys[i3]) + bf2f(ys[i3 + 1]) + bf2f(ys[i3 + 2])) * (1.f / 3.f);
            float S3 = (zs[i3] + zs[i3 + 1] + zs[i3 + 2]) * (1.f / 3.f);
            float m  = fmaxf(S1, fmaxf(S2, S3));
            float a1 = __expf(S1 - m), a2 = __expf(S2 - m), a3 = __expf(S3 - m);
            o += (a1 * C1 + a2 * C2 + a3 * C3) / (a1 + a2 + a3);
        }
        orow[d] = 0.5f * o;
    }
}

// ---------------------------------------------------------------------------
extern "C" void kernel_launch(void* const* d_in, const int* in_sizes, int n_in,
                              void* d_out, int out_size, void* d_ws, size_t ws_size,
                              hipStream_t stream) {
    const float* x       = (const float*)d_in[0];
    const float* conv_w  = (const float*)d_in[1];
    const float* conv_b  = (const float*)d_in[2];
    const float* score_w = (const float*)d_in[3];
    float* out = (float*)d_out;

    // ws (ushort units): Wtb[5*512*512] | xT[B*LPAD*E] | y[B*E*LC] | zpart fp32[8*B*8192]
    unsigned short* base = (unsigned short*)d_ws;
    unsigned short* Wtb = base;
    unsigned short* xT  = Wtb + (size_t)K_ * E_ * E_;
    unsigned short* y   = xT + (size_t)B_ * LPAD * E_;
    float*          zpart = (float*)(y + (size_t)B_ * E_ * LC);  // 16B-aligned

    wt_kernel<<<dim3((E_ * E_ * K_ + 255) / 256), 256, 0, stream>>>(conv_w, Wtb);
    xt_kernel<<<dim3(LPAD / 64, E_ / 64, B_), 256, 0, stream>>>(x, xT);
    conv_mfma<<<dim3(B_ * 16, E_ / 64), 256, 0, stream>>>(xT, Wtb, conv_b, score_w, y, zpart);
    out_kernel<<<dim3(B_ * E_), 256, 0, stream>>>(y, zpart, out);
}